// Round 3
// baseline (447.667 us; speedup 1.0000x reference)
//
#include <hip/hip_runtime.h>

typedef __attribute__((ext_vector_type(8))) short s16x8;
typedef __attribute__((ext_vector_type(4))) float f32x4;

#define B_    2
#define S_    2048
#define DIM_  2048
#define H_    16
#define KVH_  4
#define HD_   128
#define NQKV  3072

static __device__ __forceinline__ unsigned short f2bf(float f) {
  unsigned int u = __float_as_uint(f);
  u += 0x7fff + ((u >> 16) & 1);
  return (unsigned short)(u >> 16);
}
static __device__ __forceinline__ float bf2f(unsigned short h) {
  return __uint_as_float(((unsigned int)h) << 16);
}
static __device__ __forceinline__ float fexp2(float x) {
#if __has_builtin(__builtin_amdgcn_exp2f)
  return __builtin_amdgcn_exp2f(x);
#else
  return exp2f(x);
#endif
}

// ---------------- all f32 -> bf16 casts in one launch ----------------
// segments (blocks of 256 thr * 8 elems): x:4096, Wq:2048, Wk:512, Wv:512, Wo:2048
__global__ __launch_bounds__(256) void cast_all(const float* __restrict__ x,
                                                const float* __restrict__ wq,
                                                const float* __restrict__ wk,
                                                const float* __restrict__ wv,
                                                const float* __restrict__ wo,
                                                unsigned short* __restrict__ xb,
                                                unsigned short* __restrict__ wqkv,
                                                unsigned short* __restrict__ wob) {
  int blk = blockIdx.x;
  const float* s;
  unsigned short* d;
  int rel;
  if (blk < 4096)      { s = x;  d = xb;             rel = blk; }
  else if (blk < 6144) { s = wq; d = wqkv;           rel = blk - 4096; }
  else if (blk < 6656) { s = wk; d = wqkv + 4194304; rel = blk - 6144; }
  else if (blk < 7168) { s = wv; d = wqkv + 5242880; rel = blk - 6656; }
  else                 { s = wo; d = wob;            rel = blk - 7168; }
  int i = (rel * 256 + threadIdx.x) * 8;
  float4 a = *(const float4*)(s + i);
  float4 b = *(const float4*)(s + i + 4);
  uint4 o;
  o.x = (unsigned)f2bf(a.x) | ((unsigned)f2bf(a.y) << 16);
  o.y = (unsigned)f2bf(a.z) | ((unsigned)f2bf(a.w) << 16);
  o.z = (unsigned)f2bf(b.x) | ((unsigned)f2bf(b.y) << 16);
  o.w = (unsigned)f2bf(b.z) | ((unsigned)f2bf(b.w) << 16);
  *(uint4*)(d + i) = o;
}

// ---------------- m97-style GEMM: C[M,N] = A[M,K] * B[N,K]^T (+XCD swizzle) ----------------
template <bool BF16OUT>
__global__ __launch_bounds__(256) void gemm_bt(const unsigned short* __restrict__ A,
                                               const unsigned short* __restrict__ Bw,
                                               void* __restrict__ Cp, int N, int K) {
  __shared__ __align__(16) unsigned short As[128 * 32];
  __shared__ __align__(16) unsigned short Bs[128 * 32];
  const int tid = threadIdx.x;
  // bijective XCD swizzle (nwg % 8 == 0 for both call sites)
  const int gx = gridDim.x;
  const int lin = blockIdx.y * gx + blockIdx.x;
  const int cpx = (gx * gridDim.y) >> 3;
  const int nlin = (lin & 7) * cpx + (lin >> 3);
  const int n0 = (nlin % gx) * 128, m0 = (nlin / gx) * 128;
  const int w = tid >> 6, l = tid & 63;
  const int wr = w >> 1, wc = w & 1;
  const int lo = l & 15, hi = l >> 4;
  f32x4 acc[4][4] = {};
  const int KT = K >> 5;
  for (int kt = 0; kt < KT; ++kt) {
    const int k0 = kt << 5;
    __syncthreads();
#pragma unroll
    for (int c = 0; c < 2; ++c) {
      int idx = tid + c * 256;
      int row = idx >> 2, ko = (idx & 3) << 3;
      __builtin_amdgcn_global_load_lds(
          (__attribute__((address_space(1))) void*)(A + (size_t)(m0 + row) * K + k0 + ko),
          (__attribute__((address_space(3))) void*)(As + idx * 8), 16, 0, 0);
      __builtin_amdgcn_global_load_lds(
          (__attribute__((address_space(1))) void*)(Bw + (size_t)(n0 + row) * K + k0 + ko),
          (__attribute__((address_space(3))) void*)(Bs + idx * 8), 16, 0, 0);
    }
    asm volatile("s_waitcnt vmcnt(0)" ::: "memory");
    __syncthreads();
    s16x8 af[4], bfr[4];
#pragma unroll
    for (int mi = 0; mi < 4; ++mi)
      af[mi] = *(const s16x8*)(As + (wr * 64 + mi * 16 + lo) * 32 + hi * 8);
#pragma unroll
    for (int ni = 0; ni < 4; ++ni)
      bfr[ni] = *(const s16x8*)(Bs + (wc * 64 + ni * 16 + lo) * 32 + hi * 8);
#pragma unroll
    for (int mi = 0; mi < 4; ++mi)
#pragma unroll
      for (int ni = 0; ni < 4; ++ni)
        acc[mi][ni] = __builtin_amdgcn_mfma_f32_16x16x32_bf16(af[mi], bfr[ni], acc[mi][ni], 0, 0, 0);
  }
#pragma unroll
  for (int mi = 0; mi < 4; ++mi) {
#pragma unroll
    for (int ni = 0; ni < 4; ++ni) {
      int col = n0 + wc * 64 + ni * 16 + lo;
      int rowb = m0 + wr * 64 + mi * 16 + hi * 4;
#pragma unroll
      for (int r = 0; r < 4; ++r) {
        float v = acc[mi][ni][r];
        if (BF16OUT)
          ((unsigned short*)Cp)[(size_t)(rowb + r) * N + col] = f2bf(v);
        else
          ((float*)Cp)[(size_t)(rowb + r) * N + col] = v;
      }
    }
  }
}

// ---------------- RoPE + head-transpose ----------------
__global__ __launch_bounds__(256) void rope_kernel(const unsigned short* __restrict__ QKV,
                                                   const float* __restrict__ ctab,
                                                   const float* __restrict__ stab,
                                                   unsigned short* __restrict__ dst,
                                                   int nheads, int coloff, float scale) {
  int gid = blockIdx.x * 256 + threadIdx.x;
  int i = gid & 63;
  int rest = gid >> 6;
  int h = rest % nheads;
  int s = (rest / nheads) & (S_ - 1);
  int b = rest / (nheads * S_);
  const unsigned short* row = QKV + (size_t)(b * S_ + s) * NQKV + coloff + h * HD_;
  float x1 = bf2f(row[i]), x2 = bf2f(row[i + 64]);
  float c = ctab[s * 64 + i], sn = stab[s * 64 + i];
  unsigned short* drow = dst + ((size_t)(b * nheads + h) * S_ + s) * HD_;
  drow[i] = f2bf((x1 * c - x2 * sn) * scale);
  drow[i + 64] = f2bf((x1 * sn + x2 * c) * scale);
}

// ---------------- V transpose: QKV V-section -> Vt[b,kv,d,s] ----------------
__global__ __launch_bounds__(256) void vtrans_kernel(const unsigned short* __restrict__ QKV,
                                                     unsigned short* __restrict__ Vt) {
  int s0 = blockIdx.x * 64;
  int d0 = blockIdx.y * 64;
  int bk = blockIdx.z;
  int b = bk >> 2, kvh = bk & 3;
  __shared__ __align__(16) unsigned short tile[64][72];
  int tid = threadIdx.x;
  for (int e = tid; e < 512; e += 256) {
    int r = e >> 3, c = (e & 7) << 3;
    const unsigned short* src =
        QKV + (size_t)(b * S_ + s0 + r) * NQKV + 2560 + kvh * HD_ + d0 + c;
    *(uint4*)(&tile[r][c]) = *(const uint4*)src;
  }
  __syncthreads();
  for (int e = tid; e < 512; e += 256) {
    int d = e >> 3, sc = (e & 7) << 3;
    unsigned int wv[4];
#pragma unroll
    for (int j = 0; j < 4; ++j)
      wv[j] = (unsigned)tile[sc + 2 * j][d] | ((unsigned)tile[sc + 2 * j + 1][d] << 16);
    uint4 o = {wv[0], wv[1], wv[2], wv[3]};
    unsigned short* dstp = Vt + ((size_t)bk * HD_ + d0 + d) * S_ + s0 + sc;
    *(uint4*)dstp = o;
  }
}

// ---------------- flash attention: T14 async-stage + exp2 + defer-max + XCD swizzle ----------------
// 8 waves / 512 thr; wave = 16 q-rows; block q-tile = 128; KV tile = 64.
// Q pre-scaled by (1/sqrt(128))*log2(e) -> softmax in exp2 domain.
__global__ __launch_bounds__(512, 4) void attn_kernel(const unsigned short* __restrict__ Qt,
                                                      const unsigned short* __restrict__ Kt,
                                                      const unsigned short* __restrict__ Vt,
                                                      const int* __restrict__ mask,
                                                      unsigned short* __restrict__ Out) {
  // XCD swizzle: 512 blocks, 64/XCD = 4 heads sharing one kv-head -> KV L2-resident
  const int lin = (blockIdx.z * gridDim.y + blockIdx.y) * gridDim.x + blockIdx.x;
  const int nlin = (lin & 7) * 64 + (lin >> 3);
  const int qt = nlin & 15, h = (nlin >> 4) & 15, b = nlin >> 8;
  const int kvh = h >> 2;
  const int tid = threadIdx.x, w = tid >> 6, l = tid & 63;
  const int lo = l & 15, hi = l >> 4;
  const int q0 = qt * 128 + w * 16;
  const unsigned short* Qb = Qt + ((size_t)(b * H_ + h) * S_ + q0) * HD_;
  const unsigned short* Kb = Kt + (size_t)(b * KVH_ + kvh) * S_ * HD_;
  const unsigned short* Vb = Vt + (size_t)(b * KVH_ + kvh) * HD_ * S_;
  const int* mb = mask + b * S_;

  __shared__ __align__(16) unsigned short Ks[64 * 128];   // 16 KB (chunk-swizzled)
  __shared__ __align__(16) unsigned short Vs[128 * 64];   // 16 KB (chunk-swizzled)
  __shared__ __align__(16) unsigned short P_lds[8][16 * 72];  // 18 KB
  unsigned short* Pw = &P_lds[w][0];

  s16x8 qf[4];
#pragma unroll
  for (int c = 0; c < 4; ++c)
    qf[c] = *(const s16x8*)(Qb + lo * HD_ + c * 32 + hi * 8);

  // per-thread staging geometry (loop-invariant)
  int kl4[2], kchg[2], vl4[2], vchg[2], kr[2], vd[2];
#pragma unroll
  for (int c = 0; c < 2; ++c) {
    int l4 = tid + c * 512;
    kl4[c] = l4; kr[c] = l4 >> 4;
    int ch = l4 & 15;
    kchg[c] = (ch & 8) | ((ch ^ kr[c]) & 7);
    vl4[c] = l4; vd[c] = l4 >> 3;
    vchg[c] = ((l4 & 7) ^ vd[c]) & 7;
  }

  // prologue: stage tile 0 via global_load_lds
#pragma unroll
  for (int c = 0; c < 2; ++c) {
    __builtin_amdgcn_global_load_lds(
        (__attribute__((address_space(1))) void*)(Kb + (size_t)kr[c] * HD_ + kchg[c] * 8),
        (__attribute__((address_space(3))) void*)(Ks + kl4[c] * 8), 16, 0, 0);
    __builtin_amdgcn_global_load_lds(
        (__attribute__((address_space(1))) void*)(Vb + (size_t)vd[c] * S_ + vchg[c] * 8),
        (__attribute__((address_space(3))) void*)(Vs + vl4[c] * 8), 16, 0, 0);
  }
  asm volatile("s_waitcnt vmcnt(0)" ::: "memory");
  __syncthreads();

  f32x4 o[8] = {};
  float mrow[4], lrow[4];
#pragma unroll
  for (int r = 0; r < 4; ++r) { mrow[r] = -1e30f; lrow[r] = 0.f; }

  for (int t0 = 0; t0 < S_; t0 += 64) {
    const bool has_next = (t0 + 64 < S_);
    // T14: issue next tile's global loads NOW; latency hides under compute below
    uint4 kreg[2], vreg[2];
    if (has_next) {
#pragma unroll
      for (int c = 0; c < 2; ++c) {
        kreg[c] = *(const uint4*)(Kb + (size_t)(t0 + 64 + kr[c]) * HD_ + kchg[c] * 8);
        vreg[c] = *(const uint4*)(Vb + (size_t)vd[c] * S_ + t0 + 64 + vchg[c] * 8);
      }
    }
    int mv[4];
#pragma unroll
    for (int sf = 0; sf < 4; ++sf) mv[sf] = mb[t0 + sf * 16 + lo];

    // QK^T from LDS (exp2 domain; Q pre-scaled by log2e/sqrt(d))
    f32x4 s[4];
#pragma unroll
    for (int sf = 0; sf < 4; ++sf) {
      f32x4 sv = {};
      int row = sf * 16 + lo;
#pragma unroll
      for (int c = 0; c < 4; ++c) {
        int ch = c * 4 + hi;
        int chs = (ch & 8) | ((ch ^ lo) & 7);
        s16x8 kf = *(const s16x8*)(Ks + row * 128 + chs * 8);
        sv = __builtin_amdgcn_mfma_f32_16x16x32_bf16(qf[c], kf, sv, 0, 0, 0);
      }
      float bv = mv[sf] ? -1e30f : 0.0f;
#pragma unroll
      for (int r = 0; r < 4; ++r) sv[r] += bv;
      s[sf] = sv;
    }
    // online softmax, rows = q (hi*4+r), cols = k (sf*16+lo)
    float tm[4];
#pragma unroll
    for (int r = 0; r < 4; ++r)
      tm[r] = fmaxf(fmaxf(s[0][r], s[1][r]), fmaxf(s[2][r], s[3][r]));
#pragma unroll
    for (int d = 1; d < 16; d <<= 1)
#pragma unroll
      for (int r = 0; r < 4; ++r) tm[r] = fmaxf(tm[r], __shfl_xor(tm[r], d));
    // T13 defer-max: skip rescale while growth <= 8 (p bounded by 2^8)
    float dm = tm[0] - mrow[0];
#pragma unroll
    for (int r = 1; r < 4; ++r) dm = fmaxf(dm, tm[r] - mrow[r]);
    if (!__all(dm <= 8.0f)) {
      float sc_[4];
#pragma unroll
      for (int r = 0; r < 4; ++r) {
        float mnew = fmaxf(mrow[r], tm[r]);
        sc_[r] = fexp2(mrow[r] - mnew);
        mrow[r] = mnew;
        lrow[r] *= sc_[r];
      }
#pragma unroll
      for (int df = 0; df < 8; ++df)
#pragma unroll
        for (int r = 0; r < 4; ++r) o[df][r] *= sc_[r];
    }
    float ts[4] = {0.f, 0.f, 0.f, 0.f};
#pragma unroll
    for (int sf = 0; sf < 4; ++sf)
#pragma unroll
      for (int r = 0; r < 4; ++r) {
        float p = fexp2(s[sf][r] - mrow[r]);
        ts[r] += p;
        Pw[(hi * 4 + r) * 72 + sf * 16 + lo] = f2bf(p);
      }
#pragma unroll
    for (int d = 1; d < 16; d <<= 1)
#pragma unroll
      for (int r = 0; r < 4; ++r) ts[r] += __shfl_xor(ts[r], d);
#pragma unroll
    for (int r = 0; r < 4; ++r) lrow[r] += ts[r];
    // P: C-layout -> A-layout via per-wave LDS
    s16x8 pa[2];
#pragma unroll
    for (int kk = 0; kk < 2; ++kk)
      pa[kk] = *(const s16x8*)(Pw + lo * 72 + kk * 32 + hi * 8);
    // PV from LDS
#pragma unroll
    for (int df = 0; df < 8; ++df) {
      int d = df * 16 + lo;
#pragma unroll
      for (int kk = 0; kk < 2; ++kk) {
        int ch = kk * 4 + hi;
        int chs = (ch ^ lo) & 7;
        s16x8 vf = *(const s16x8*)(Vs + d * 64 + chs * 8);
        o[df] = __builtin_amdgcn_mfma_f32_16x16x32_bf16(pa[kk], vf, o[df], 0, 0, 0);
      }
    }
    __syncthreads();  // all waves done reading Ks/Vs for this tile
    if (has_next) {
#pragma unroll
      for (int c = 0; c < 2; ++c) {
        *(uint4*)(Ks + kl4[c] * 8) = kreg[c];
        *(uint4*)(Vs + vl4[c] * 8) = vreg[c];
      }
    }
    __syncthreads();  // staged writes visible
  }
  float inv[4];
#pragma unroll
  for (int r = 0; r < 4; ++r) inv[r] = 1.0f / lrow[r];
#pragma unroll
  for (int df = 0; df < 8; ++df)
#pragma unroll
    for (int r = 0; r < 4; ++r)
      Out[(size_t)(b * S_ + q0 + hi * 4 + r) * DIM_ + h * HD_ + df * 16 + lo] =
          f2bf(o[df][r] * inv[r]);
}

extern "C" void kernel_launch(void* const* d_in, const int* in_sizes, int n_in,
                              void* d_out, int out_size, void* d_ws, size_t ws_size,
                              hipStream_t stream) {
  (void)in_sizes; (void)n_in; (void)out_size; (void)ws_size;
  const float* x    = (const float*)d_in[0];
  const float* ctab = (const float*)d_in[1];
  const float* stab = (const float*)d_in[2];
  const int*   mask = (const int*)d_in[3];
  const float* Wq   = (const float*)d_in[4];
  const float* Wk   = (const float*)d_in[5];
  const float* Wv   = (const float*)d_in[6];
  const float* Wo   = (const float*)d_in[7];

  unsigned short* x_bf = (unsigned short*)d_ws;        // 8388608 elems (reused as attn_out)
  unsigned short* Wqkv = x_bf + 8388608;               // 6291456
  unsigned short* Wob  = Wqkv + 6291456;               // 4194304
  unsigned short* QKV  = Wob + 4194304;                // 12582912
  unsigned short* Qt   = QKV + 12582912;               // 8388608
  unsigned short* Kt   = Qt + 8388608;                 // 2097152
  unsigned short* Vt   = Kt + 2097152;                 // 2097152

  cast_all<<<9216, 256, 0, stream>>>(x, Wq, Wk, Wv, Wo, x_bf, Wqkv, Wob);

  gemm_bt<true><<<dim3(24, 32), 256, 0, stream>>>(x_bf, Wqkv, QKV, NQKV, DIM_);

  // Q pre-scale includes log2(e) for exp2-domain softmax
  rope_kernel<<<16384, 256, 0, stream>>>(QKV, ctab, stab, Qt, H_, 0,
                                         0.08838834764831845f * 1.4426950408889634f);
  rope_kernel<<<4096, 256, 0, stream>>>(QKV, ctab, stab, Kt, KVH_, DIM_, 1.0f);
  vtrans_kernel<<<dim3(32, 2, 8), 256, 0, stream>>>(QKV, Vt);

  attn_kernel<<<dim3(16, 16, 2), 512, 0, stream>>>(Qt, Kt, Vt, mask, x_bf);

  gemm_bt<false><<<dim3(16, 32), 256, 0, stream>>>(x_bf, Wob, d_out, DIM_, DIM_);
}

// Round 5
// 421.900 us; speedup vs baseline: 1.0611x; 1.0611x over previous
//
#include <hip/hip_runtime.h>

typedef __attribute__((ext_vector_type(8))) short s16x8;
typedef __attribute__((ext_vector_type(4))) float f32x4;

#define B_    2
#define S_    2048
#define DIM_  2048
#define H_    16
#define KVH_  4
#define HD_   128
#define NQKV  3072

static __device__ __forceinline__ unsigned short f2bf(float f) {
  unsigned int u = __float_as_uint(f);
  u += 0x7fff + ((u >> 16) & 1);
  return (unsigned short)(u >> 16);
}
static __device__ __forceinline__ float bf2f(unsigned short h) {
  return __uint_as_float(((unsigned int)h) << 16);
}
static __device__ __forceinline__ float fexp2(float x) {
#if __has_builtin(__builtin_amdgcn_exp2f)
  return __builtin_amdgcn_exp2f(x);
#else
  return exp2f(x);
#endif
}

// ---------------- all f32 -> bf16 casts in one launch ----------------
__global__ __launch_bounds__(256) void cast_all(const float* __restrict__ x,
                                                const float* __restrict__ wq,
                                                const float* __restrict__ wk,
                                                const float* __restrict__ wv,
                                                const float* __restrict__ wo,
                                                unsigned short* __restrict__ xb,
                                                unsigned short* __restrict__ wqkv,
                                                unsigned short* __restrict__ wob) {
  int blk = blockIdx.x;
  const float* s;
  unsigned short* d;
  int rel;
  if (blk < 4096)      { s = x;  d = xb;             rel = blk; }
  else if (blk < 6144) { s = wq; d = wqkv;           rel = blk - 4096; }
  else if (blk < 6656) { s = wk; d = wqkv + 4194304; rel = blk - 6144; }
  else if (blk < 7168) { s = wv; d = wqkv + 5242880; rel = blk - 6656; }
  else                 { s = wo; d = wob;            rel = blk - 7168; }
  int i = (rel * 256 + threadIdx.x) * 8;
  float4 a = *(const float4*)(s + i);
  float4 b = *(const float4*)(s + i + 4);
  uint4 o;
  o.x = (unsigned)f2bf(a.x) | ((unsigned)f2bf(a.y) << 16);
  o.y = (unsigned)f2bf(a.z) | ((unsigned)f2bf(a.w) << 16);
  o.z = (unsigned)f2bf(b.x) | ((unsigned)f2bf(b.y) << 16);
  o.w = (unsigned)f2bf(b.z) | ((unsigned)f2bf(b.w) << 16);
  *(uint4*)(d + i) = o;
}

// ---------------- m97-style GEMM: C[M,N] = A[M,K] * B[N,K]^T (+XCD swizzle) ----------------
template <bool BF16OUT>
__global__ __launch_bounds__(256) void gemm_bt(const unsigned short* __restrict__ A,
                                               const unsigned short* __restrict__ Bw,
                                               void* __restrict__ Cp, int N, int K) {
  __shared__ __align__(16) unsigned short As[128 * 32];
  __shared__ __align__(16) unsigned short Bs[128 * 32];
  const int tid = threadIdx.x;
  const int gx = gridDim.x;
  const int lin = blockIdx.y * gx + blockIdx.x;
  const int cpx = (gx * gridDim.y) >> 3;
  const int nlin = (lin & 7) * cpx + (lin >> 3);
  const int n0 = (nlin % gx) * 128, m0 = (nlin / gx) * 128;
  const int w = tid >> 6, l = tid & 63;
  const int wr = w >> 1, wc = w & 1;
  const int lo = l & 15, hi = l >> 4;
  f32x4 acc[4][4] = {};
  const int KT = K >> 5;
  for (int kt = 0; kt < KT; ++kt) {
    const int k0 = kt << 5;
    __syncthreads();
#pragma unroll
    for (int c = 0; c < 2; ++c) {
      int idx = tid + c * 256;
      int row = idx >> 2, ko = (idx & 3) << 3;
      __builtin_amdgcn_global_load_lds(
          (__attribute__((address_space(1))) void*)(A + (size_t)(m0 + row) * K + k0 + ko),
          (__attribute__((address_space(3))) void*)(As + idx * 8), 16, 0, 0);
      __builtin_amdgcn_global_load_lds(
          (__attribute__((address_space(1))) void*)(Bw + (size_t)(n0 + row) * K + k0 + ko),
          (__attribute__((address_space(3))) void*)(Bs + idx * 8), 16, 0, 0);
    }
    asm volatile("s_waitcnt vmcnt(0)" ::: "memory");
    __syncthreads();
    s16x8 af[4], bfr[4];
#pragma unroll
    for (int mi = 0; mi < 4; ++mi)
      af[mi] = *(const s16x8*)(As + (wr * 64 + mi * 16 + lo) * 32 + hi * 8);
#pragma unroll
    for (int ni = 0; ni < 4; ++ni)
      bfr[ni] = *(const s16x8*)(Bs + (wc * 64 + ni * 16 + lo) * 32 + hi * 8);
#pragma unroll
    for (int mi = 0; mi < 4; ++mi)
#pragma unroll
      for (int ni = 0; ni < 4; ++ni)
        acc[mi][ni] = __builtin_amdgcn_mfma_f32_16x16x32_bf16(af[mi], bfr[ni], acc[mi][ni], 0, 0, 0);
  }
#pragma unroll
  for (int mi = 0; mi < 4; ++mi) {
#pragma unroll
    for (int ni = 0; ni < 4; ++ni) {
      int col = n0 + wc * 64 + ni * 16 + lo;
      int rowb = m0 + wr * 64 + mi * 16 + hi * 4;
#pragma unroll
      for (int r = 0; r < 4; ++r) {
        float v = acc[mi][ni][r];
        if (BF16OUT)
          ((unsigned short*)Cp)[(size_t)(rowb + r) * N + col] = f2bf(v);
        else
          ((float*)Cp)[(size_t)(rowb + r) * N + col] = v;
      }
    }
  }
}

// ---------------- RoPE + head-transpose ----------------
__global__ __launch_bounds__(256) void rope_kernel(const unsigned short* __restrict__ QKV,
                                                   const float* __restrict__ ctab,
                                                   const float* __restrict__ stab,
                                                   unsigned short* __restrict__ dst,
                                                   int nheads, int coloff, float scale) {
  int gid = blockIdx.x * 256 + threadIdx.x;
  int i = gid & 63;
  int rest = gid >> 6;
  int h = rest % nheads;
  int s = (rest / nheads) & (S_ - 1);
  int b = rest / (nheads * S_);
  const unsigned short* row = QKV + (size_t)(b * S_ + s) * NQKV + coloff + h * HD_;
  float x1 = bf2f(row[i]), x2 = bf2f(row[i + 64]);
  float c = ctab[s * 64 + i], sn = stab[s * 64 + i];
  unsigned short* drow = dst + ((size_t)(b * nheads + h) * S_ + s) * HD_;
  drow[i] = f2bf((x1 * c - x2 * sn) * scale);
  drow[i + 64] = f2bf((x1 * sn + x2 * c) * scale);
}

// ---------------- V transpose: QKV V-section -> Vt[b,kv,d,s] ----------------
__global__ __launch_bounds__(256) void vtrans_kernel(const unsigned short* __restrict__ QKV,
                                                     unsigned short* __restrict__ Vt) {
  int s0 = blockIdx.x * 64;
  int d0 = blockIdx.y * 64;
  int bk = blockIdx.z;
  int b = bk >> 2, kvh = bk & 3;
  __shared__ __align__(16) unsigned short tile[64][72];
  int tid = threadIdx.x;
  for (int e = tid; e < 512; e += 256) {
    int r = e >> 3, c = (e & 7) << 3;
    const unsigned short* src =
        QKV + (size_t)(b * S_ + s0 + r) * NQKV + 2560 + kvh * HD_ + d0 + c;
    *(uint4*)(&tile[r][c]) = *(const uint4*)src;
  }
  __syncthreads();
  for (int e = tid; e < 512; e += 256) {
    int d = e >> 3, sc = (e & 7) << 3;
    unsigned int wv[4];
#pragma unroll
    for (int j = 0; j < 4; ++j)
      wv[j] = (unsigned)tile[sc + 2 * j][d] | ((unsigned)tile[sc + 2 * j + 1][d] << 16);
    uint4 o = {wv[0], wv[1], wv[2], wv[3]};
    unsigned short* dstp = Vt + ((size_t)bk * HD_ + d0 + d) * S_ + s0 + sc;
    *(uint4*)dstp = o;
  }
}

// ---------------- flash attention: double-buffered LDS, prefetch-at-top ----------------
// 8 waves / 512 thr; wave = 16 q-rows; block q-tile = 128; KV tile = 64.
// T3 minimum-2-phase: issue next tile's global_load_lds into buf^1 BEFORE compute on buf;
// one __syncthreads() per tile at the end (vmcnt drain is hidden under the compute).
// No inline asm in the loop -> no scheduler/ordering hazards.
__global__ __launch_bounds__(512) void attn_kernel(const unsigned short* __restrict__ Qt,
                                                   const unsigned short* __restrict__ Kt,
                                                   const unsigned short* __restrict__ Vt,
                                                   const int* __restrict__ mask,
                                                   unsigned short* __restrict__ Out) {
  // XCD swizzle: 512 blocks, 64/XCD = 4 heads sharing one kv-head -> KV L2-resident
  const int lin = (blockIdx.z * gridDim.y + blockIdx.y) * gridDim.x + blockIdx.x;
  const int nlin = (lin & 7) * 64 + (lin >> 3);
  const int qt = nlin & 15, h = (nlin >> 4) & 15, b = nlin >> 8;
  const int kvh = h >> 2;
  const int tid = threadIdx.x, w = tid >> 6, l = tid & 63;
  const int lo = l & 15, hi = l >> 4;
  const int q0 = qt * 128 + w * 16;
  const unsigned short* Qb = Qt + ((size_t)(b * H_ + h) * S_ + q0) * HD_;
  const unsigned short* Kb = Kt + (size_t)(b * KVH_ + kvh) * S_ * HD_;
  const unsigned short* Vb = Vt + (size_t)(b * KVH_ + kvh) * HD_ * S_;
  const int* mb = mask + b * S_;

  __shared__ __align__(16) unsigned short Ks[2][64 * 128];    // 32 KB (chunk-swizzled)
  __shared__ __align__(16) unsigned short Vs[2][128 * 64];    // 32 KB (chunk-swizzled)
  __shared__ __align__(16) unsigned short P_lds[8][16 * 80];  // 20 KB
  unsigned short* Pw = &P_lds[w][0];

  s16x8 qf[4];
#pragma unroll
  for (int c = 0; c < 4; ++c)
    qf[c] = *(const s16x8*)(Qb + lo * HD_ + c * 32 + hi * 8);

  // per-thread staging geometry (loop-invariant)
  int kl4[2], kchg[2], vl4[2], vchg[2], kr[2], vd[2];
#pragma unroll
  for (int c = 0; c < 2; ++c) {
    int l4 = tid + c * 512;
    kl4[c] = l4; kr[c] = l4 >> 4;
    int ch = l4 & 15;
    kchg[c] = (ch & 8) | ((ch ^ kr[c]) & 7);
    vl4[c] = l4; vd[c] = l4 >> 3;
    vchg[c] = ((l4 & 7) ^ vd[c]) & 7;
  }

  // prologue: stage tile 0 into buffer 0
#pragma unroll
  for (int c = 0; c < 2; ++c) {
    __builtin_amdgcn_global_load_lds(
        (__attribute__((address_space(1))) void*)(Kb + (size_t)kr[c] * HD_ + kchg[c] * 8),
        (__attribute__((address_space(3))) void*)(&Ks[0][0] + kl4[c] * 8), 16, 0, 0);
    __builtin_amdgcn_global_load_lds(
        (__attribute__((address_space(1))) void*)(Vb + (size_t)vd[c] * S_ + vchg[c] * 8),
        (__attribute__((address_space(3))) void*)(&Vs[0][0] + vl4[c] * 8), 16, 0, 0);
  }
  __syncthreads();

  f32x4 o[8] = {};
  float mrow[4], lrow[4];
#pragma unroll
  for (int r = 0; r < 4; ++r) { mrow[r] = -1e30f; lrow[r] = 0.f; }

  int buf = 0;
  for (int t0 = 0; t0 < S_; t0 += 64, buf ^= 1) {
    // prefetch next tile into buf^1; latency hides under this tile's compute
    if (t0 + 64 < S_) {
#pragma unroll
      for (int c = 0; c < 2; ++c) {
        __builtin_amdgcn_global_load_lds(
            (__attribute__((address_space(1))) void*)(Kb + (size_t)(t0 + 64 + kr[c]) * HD_ + kchg[c] * 8),
            (__attribute__((address_space(3))) void*)(&Ks[buf ^ 1][0] + kl4[c] * 8), 16, 0, 0);
        __builtin_amdgcn_global_load_lds(
            (__attribute__((address_space(1))) void*)(Vb + (size_t)vd[c] * S_ + t0 + 64 + vchg[c] * 8),
            (__attribute__((address_space(3))) void*)(&Vs[buf ^ 1][0] + vl4[c] * 8), 16, 0, 0);
      }
    }
    int mv[4];
#pragma unroll
    for (int sf = 0; sf < 4; ++sf) mv[sf] = mb[t0 + sf * 16 + lo];

    // ---- QK^T from Ks[buf] (exp2 domain; Q pre-scaled by log2e/sqrt(d)) ----
    const unsigned short* Kcur = &Ks[buf][0];
    const unsigned short* Vcur = &Vs[buf][0];
    f32x4 s[4];
#pragma unroll
    for (int sf = 0; sf < 4; ++sf) {
      f32x4 sv = {};
      int row = sf * 16 + lo;
#pragma unroll
      for (int c = 0; c < 4; ++c) {
        int ch = c * 4 + hi;
        int chs = (ch & 8) | ((ch ^ lo) & 7);
        s16x8 kf = *(const s16x8*)(Kcur + row * 128 + chs * 8);
        sv = __builtin_amdgcn_mfma_f32_16x16x32_bf16(qf[c], kf, sv, 0, 0, 0);
      }
      float bv = mv[sf] ? -1e30f : 0.0f;
#pragma unroll
      for (int r = 0; r < 4; ++r) sv[r] += bv;
      s[sf] = sv;
    }

    // ---- online softmax (rows = q hi*4+r, cols = k sf*16+lo) ----
    float tm[4];
#pragma unroll
    for (int r = 0; r < 4; ++r)
      tm[r] = fmaxf(fmaxf(s[0][r], s[1][r]), fmaxf(s[2][r], s[3][r]));
#pragma unroll
    for (int d = 1; d < 16; d <<= 1)
#pragma unroll
      for (int r = 0; r < 4; ++r) tm[r] = fmaxf(tm[r], __shfl_xor(tm[r], d));
    float dm = tm[0] - mrow[0];
#pragma unroll
    for (int r = 1; r < 4; ++r) dm = fmaxf(dm, tm[r] - mrow[r]);
    if (!__all(dm <= 8.0f)) {  // T13 defer-max
      float sc_[4];
#pragma unroll
      for (int r = 0; r < 4; ++r) {
        float mnew = fmaxf(mrow[r], tm[r]);
        sc_[r] = fexp2(mrow[r] - mnew);
        mrow[r] = mnew;
        lrow[r] *= sc_[r];
      }
#pragma unroll
      for (int df = 0; df < 8; ++df)
#pragma unroll
        for (int r = 0; r < 4; ++r) o[df][r] *= sc_[r];
    }
    float ts[4] = {0.f, 0.f, 0.f, 0.f};
#pragma unroll
    for (int sf = 0; sf < 4; ++sf)
#pragma unroll
      for (int r = 0; r < 4; ++r) {
        float p = fexp2(s[sf][r] - mrow[r]);
        ts[r] += p;
        Pw[(hi * 4 + r) * 80 + sf * 16 + lo] = f2bf(p);
      }
#pragma unroll
    for (int d = 1; d < 16; d <<= 1)
#pragma unroll
      for (int r = 0; r < 4; ++r) ts[r] += __shfl_xor(ts[r], d);
#pragma unroll
    for (int r = 0; r < 4; ++r) lrow[r] += ts[r];
    // P: C-layout -> A-layout via per-wave LDS (in-wave DS ordering suffices)
    s16x8 pa[2];
#pragma unroll
    for (int kk = 0; kk < 2; ++kk)
      pa[kk] = *(const s16x8*)(Pw + lo * 80 + kk * 32 + hi * 8);

    // ---- PV from Vs[buf] ----
#pragma unroll
    for (int df = 0; df < 8; ++df) {
      int d = df * 16 + lo;
#pragma unroll
      for (int kk = 0; kk < 2; ++kk) {
        int ch = kk * 4 + hi;
        int chs = (ch ^ lo) & 7;
        s16x8 vf = *(const s16x8*)(Vcur + d * 64 + chs * 8);
        o[df] = __builtin_amdgcn_mfma_f32_16x16x32_bf16(pa[kk], vf, o[df], 0, 0, 0);
      }
    }
    // one barrier per tile: drains prefetch (hidden under compute above) and
    // guarantees all waves are done reading buf before it's overwritten next iter
    __syncthreads();
  }

  float inv[4];
#pragma unroll
  for (int r = 0; r < 4; ++r) inv[r] = 1.0f / lrow[r];
#pragma unroll
  for (int df = 0; df < 8; ++df)
#pragma unroll
    for (int r = 0; r < 4; ++r)
      Out[(size_t)(b * S_ + q0 + hi * 4 + r) * DIM_ + h * HD_ + df * 16 + lo] =
          f2bf(o[df][r] * inv[r]);
}

extern "C" void kernel_launch(void* const* d_in, const int* in_sizes, int n_in,
                              void* d_out, int out_size, void* d_ws, size_t ws_size,
                              hipStream_t stream) {
  (void)in_sizes; (void)n_in; (void)out_size; (void)ws_size;
  const float* x    = (const float*)d_in[0];
  const float* ctab = (const float*)d_in[1];
  const float* stab = (const float*)d_in[2];
  const int*   mask = (const int*)d_in[3];
  const float* Wq   = (const float*)d_in[4];
  const float* Wk   = (const float*)d_in[5];
  const float* Wv   = (const float*)d_in[6];
  const float* Wo   = (const float*)d_in[7];

  unsigned short* x_bf = (unsigned short*)d_ws;        // 8388608 elems (reused as attn_out)
  unsigned short* Wqkv = x_bf + 8388608;               // 6291456
  unsigned short* Wob  = Wqkv + 6291456;               // 4194304
  unsigned short* QKV  = Wob + 4194304;                // 12582912
  unsigned short* Qt   = QKV + 12582912;               // 8388608
  unsigned short* Kt   = Qt + 8388608;                 // 2097152
  unsigned short* Vt   = Kt + 2097152;                 // 2097152

  cast_all<<<9216, 256, 0, stream>>>(x, Wq, Wk, Wv, Wo, x_bf, Wqkv, Wob);

  gemm_bt<true><<<dim3(24, 32), 256, 0, stream>>>(x_bf, Wqkv, QKV, NQKV, DIM_);

  // Q pre-scale includes log2(e) for exp2-domain softmax
  rope_kernel<<<16384, 256, 0, stream>>>(QKV, ctab, stab, Qt, H_, 0,
                                         0.08838834764831845f * 1.4426950408889634f);
  rope_kernel<<<4096, 256, 0, stream>>>(QKV, ctab, stab, Kt, KVH_, DIM_, 1.0f);
  vtrans_kernel<<<dim3(32, 2, 8), 256, 0, stream>>>(QKV, Vt);

  attn_kernel<<<dim3(16, 16, 2), 512, 0, stream>>>(Qt, Kt, Vt, mask, x_bf);

  gemm_bt<false><<<dim3(16, 32), 256, 0, stream>>>(x_bf, Wob, d_out, DIM_, DIM_);
}

// Round 6
// 337.133 us; speedup vs baseline: 1.3279x; 1.2514x over previous
//
#include <hip/hip_runtime.h>

typedef __attribute__((ext_vector_type(8))) short s16x8;
typedef __attribute__((ext_vector_type(4))) float f32x4;

#define B_    2
#define S_    2048
#define DIM_  2048
#define H_    16
#define KVH_  4
#define HD_   128
#define NQKV  3072

static __device__ __forceinline__ unsigned short f2bf(float f) {
  unsigned int u = __float_as_uint(f);
  u += 0x7fff + ((u >> 16) & 1);
  return (unsigned short)(u >> 16);
}
static __device__ __forceinline__ float bf2f(unsigned short h) {
  return __uint_as_float(((unsigned int)h) << 16);
}
static __device__ __forceinline__ float fexp2(float x) {
#if __has_builtin(__builtin_amdgcn_exp2f)
  return __builtin_amdgcn_exp2f(x);
#else
  return exp2f(x);
#endif
}

// ---------------- all f32 -> bf16 casts in one launch ----------------
__global__ __launch_bounds__(256) void cast_all(const float* __restrict__ x,
                                                const float* __restrict__ wq,
                                                const float* __restrict__ wk,
                                                const float* __restrict__ wv,
                                                const float* __restrict__ wo,
                                                unsigned short* __restrict__ xb,
                                                unsigned short* __restrict__ wqkv,
                                                unsigned short* __restrict__ wob) {
  int blk = blockIdx.x;
  const float* s;
  unsigned short* d;
  int rel;
  if (blk < 4096)      { s = x;  d = xb;             rel = blk; }
  else if (blk < 6144) { s = wq; d = wqkv;           rel = blk - 4096; }
  else if (blk < 6656) { s = wk; d = wqkv + 4194304; rel = blk - 6144; }
  else if (blk < 7168) { s = wv; d = wqkv + 5242880; rel = blk - 6656; }
  else                 { s = wo; d = wob;            rel = blk - 7168; }
  int i = (rel * 256 + threadIdx.x) * 8;
  float4 a = *(const float4*)(s + i);
  float4 b = *(const float4*)(s + i + 4);
  uint4 o;
  o.x = (unsigned)f2bf(a.x) | ((unsigned)f2bf(a.y) << 16);
  o.y = (unsigned)f2bf(a.z) | ((unsigned)f2bf(a.w) << 16);
  o.z = (unsigned)f2bf(b.x) | ((unsigned)f2bf(b.y) << 16);
  o.w = (unsigned)f2bf(b.z) | ((unsigned)f2bf(b.w) << 16);
  *(uint4*)(d + i) = o;
}

// ---------------- mask prefix-scan: posmap[b][s] = compact slot or -1; cnts[b] ----------------
__global__ __launch_bounds__(256) void scan_mask(const int* __restrict__ mask,
                                                 int* __restrict__ posmap,
                                                 int* __restrict__ cnts) {
  int b = blockIdx.x;
  __shared__ int a0[S_], a1[S_];
  int tid = threadIdx.x;
  for (int i = tid; i < S_; i += 256) a0[i] = (mask[b * S_ + i] == 0) ? 1 : 0;
  __syncthreads();
  int* src = a0;
  int* dst = a1;
  for (int off = 1; off < S_; off <<= 1) {
    for (int i = tid; i < S_; i += 256)
      dst[i] = src[i] + (i >= off ? src[i - off] : 0);
    __syncthreads();
    int* t = src; src = dst; dst = t;
  }
  for (int i = tid; i < S_; i += 256)
    posmap[b * S_ + i] = (mask[b * S_ + i] == 0) ? (src[i] - 1) : -1;
  if (tid == 0) cnts[b] = src[S_ - 1];
}

// ---------------- m97-style GEMM: C[M,N] = A[M,K] * B[N,K]^T (+XCD swizzle) ----------------
template <bool BF16OUT>
__global__ __launch_bounds__(256) void gemm_bt(const unsigned short* __restrict__ A,
                                               const unsigned short* __restrict__ Bw,
                                               void* __restrict__ Cp, int N, int K) {
  __shared__ __align__(16) unsigned short As[128 * 32];
  __shared__ __align__(16) unsigned short Bs[128 * 32];
  const int tid = threadIdx.x;
  const int gx = gridDim.x;
  const int lin = blockIdx.y * gx + blockIdx.x;
  const int cpx = (gx * gridDim.y) >> 3;
  const int nlin = (lin & 7) * cpx + (lin >> 3);
  const int n0 = (nlin % gx) * 128, m0 = (nlin / gx) * 128;
  const int w = tid >> 6, l = tid & 63;
  const int wr = w >> 1, wc = w & 1;
  const int lo = l & 15, hi = l >> 4;
  f32x4 acc[4][4] = {};
  const int KT = K >> 5;
  for (int kt = 0; kt < KT; ++kt) {
    const int k0 = kt << 5;
    __syncthreads();
#pragma unroll
    for (int c = 0; c < 2; ++c) {
      int idx = tid + c * 256;
      int row = idx >> 2, ko = (idx & 3) << 3;
      __builtin_amdgcn_global_load_lds(
          (__attribute__((address_space(1))) void*)(A + (size_t)(m0 + row) * K + k0 + ko),
          (__attribute__((address_space(3))) void*)(As + idx * 8), 16, 0, 0);
      __builtin_amdgcn_global_load_lds(
          (__attribute__((address_space(1))) void*)(Bw + (size_t)(n0 + row) * K + k0 + ko),
          (__attribute__((address_space(3))) void*)(Bs + idx * 8), 16, 0, 0);
    }
    asm volatile("s_waitcnt vmcnt(0)" ::: "memory");
    __syncthreads();
    s16x8 af[4], bfr[4];
#pragma unroll
    for (int mi = 0; mi < 4; ++mi)
      af[mi] = *(const s16x8*)(As + (wr * 64 + mi * 16 + lo) * 32 + hi * 8);
#pragma unroll
    for (int ni = 0; ni < 4; ++ni)
      bfr[ni] = *(const s16x8*)(Bs + (wc * 64 + ni * 16 + lo) * 32 + hi * 8);
#pragma unroll
    for (int mi = 0; mi < 4; ++mi)
#pragma unroll
      for (int ni = 0; ni < 4; ++ni)
        acc[mi][ni] = __builtin_amdgcn_mfma_f32_16x16x32_bf16(af[mi], bfr[ni], acc[mi][ni], 0, 0, 0);
  }
#pragma unroll
  for (int mi = 0; mi < 4; ++mi) {
#pragma unroll
    for (int ni = 0; ni < 4; ++ni) {
      int col = n0 + wc * 64 + ni * 16 + lo;
      int rowb = m0 + wr * 64 + mi * 16 + hi * 4;
#pragma unroll
      for (int r = 0; r < 4; ++r) {
        float v = acc[mi][ni][r];
        if (BF16OUT)
          ((unsigned short*)Cp)[(size_t)(rowb + r) * N + col] = f2bf(v);
        else
          ((float*)Cp)[(size_t)(rowb + r) * N + col] = v;
      }
    }
  }
}

// ---------------- RoPE Q: QKV[b,s,h*128+d] -> Qt[b,h,s,d], scaled ----------------
__global__ __launch_bounds__(256) void rope_q(const unsigned short* __restrict__ QKV,
                                              const float* __restrict__ ctab,
                                              const float* __restrict__ stab,
                                              unsigned short* __restrict__ dst, float scale) {
  int gid = blockIdx.x * 256 + threadIdx.x;
  int i = gid & 63;
  int rest = gid >> 6;
  int h = rest & 15;
  int s = (rest >> 4) & (S_ - 1);
  int b = rest >> 15;
  const unsigned short* row = QKV + (size_t)(b * S_ + s) * NQKV + h * HD_;
  float x1 = bf2f(row[i]), x2 = bf2f(row[i + 64]);
  float c = ctab[s * 64 + i], sn = stab[s * 64 + i];
  unsigned short* drow = dst + ((size_t)(b * H_ + h) * S_ + s) * HD_;
  drow[i] = f2bf((x1 * c - x2 * sn) * scale);
  drow[i + 64] = f2bf((x1 * sn + x2 * c) * scale);
}

// ---------------- RoPE K + compaction: write only unmasked s, at posmap[s] ----------------
__global__ __launch_bounds__(256) void rope_k(const unsigned short* __restrict__ QKV,
                                              const float* __restrict__ ctab,
                                              const float* __restrict__ stab,
                                              const int* __restrict__ posmap,
                                              unsigned short* __restrict__ dst) {
  int gid = blockIdx.x * 256 + threadIdx.x;
  int i = gid & 63;
  int rest = gid >> 6;
  int h = rest & 3;
  int s = (rest >> 2) & (S_ - 1);
  int b = rest >> 13;
  int sp = posmap[b * S_ + s];
  if (sp < 0) return;
  const unsigned short* row = QKV + (size_t)(b * S_ + s) * NQKV + DIM_ + h * HD_;
  float x1 = bf2f(row[i]), x2 = bf2f(row[i + 64]);
  float c = ctab[s * 64 + i], sn = stab[s * 64 + i];
  unsigned short* drow = dst + ((size_t)(b * KVH_ + h) * S_ + sp) * HD_;
  drow[i] = f2bf(x1 * c - x2 * sn);
  drow[i + 64] = f2bf(x1 * sn + x2 * c);
}

// ---------------- V transpose + compaction: QKV V-section -> Vt[b,kv,d,posmap[s]] ----------------
__global__ __launch_bounds__(256) void vtrans_kernel(const unsigned short* __restrict__ QKV,
                                                     const int* __restrict__ posmap,
                                                     unsigned short* __restrict__ Vt) {
  int s0 = blockIdx.x * 64;
  int d0 = blockIdx.y * 64;
  int bk = blockIdx.z;
  int b = bk >> 2, kvh = bk & 3;
  __shared__ __align__(16) unsigned short tile[64][72];
  __shared__ int pm[64];
  int tid = threadIdx.x;
  if (tid < 64) pm[tid] = posmap[b * S_ + s0 + tid];
  for (int e = tid; e < 512; e += 256) {
    int r = e >> 3, c = (e & 7) << 3;
    const unsigned short* src =
        QKV + (size_t)(b * S_ + s0 + r) * NQKV + 2560 + kvh * HD_ + d0 + c;
    *(uint4*)(&tile[r][c]) = *(const uint4*)src;
  }
  __syncthreads();
  for (int e = tid; e < 512; e += 256) {
    int d = e >> 3, scb = (e & 7) << 3;
    unsigned short* dstrow = Vt + ((size_t)bk * HD_ + d0 + d) * S_;
#pragma unroll
    for (int j = 0; j < 8; ++j) {
      int sp = pm[scb + j];
      if (sp >= 0) dstrow[sp] = tile[scb + j][d];
    }
  }
}

// ---------------- flash attention over COMPACTED K/V (r2-proven serial-stage structure) ----------------
// 8 waves / 512 thr; wave = 16 q-rows; block q-tile = 128; KV tile = 64; loop bound cnt[b].
__global__ __launch_bounds__(512) void attn_kernel(const unsigned short* __restrict__ Qt,
                                                   const unsigned short* __restrict__ Kt,
                                                   const unsigned short* __restrict__ Vt,
                                                   const int* __restrict__ cnts,
                                                   unsigned short* __restrict__ Out) {
  // XCD swizzle: 512 blocks, 64/XCD = 4 heads sharing one kv-head -> KV L2-resident
  const int lin = (blockIdx.z * gridDim.y + blockIdx.y) * gridDim.x + blockIdx.x;
  const int nlin = (lin & 7) * 64 + (lin >> 3);
  const int qt = nlin & 15, h = (nlin >> 4) & 15, b = nlin >> 8;
  const int kvh = h >> 2;
  const int cnt = cnts[b];
  const int tid = threadIdx.x, w = tid >> 6, l = tid & 63;
  const int lo = l & 15, hi = l >> 4;
  const int q0 = qt * 128 + w * 16;
  const unsigned short* Qb = Qt + ((size_t)(b * H_ + h) * S_ + q0) * HD_;
  const unsigned short* Kb = Kt + (size_t)(b * KVH_ + kvh) * S_ * HD_;
  const unsigned short* Vb = Vt + (size_t)(b * KVH_ + kvh) * HD_ * S_;

  __shared__ __align__(16) unsigned short Ks[64 * 128];       // 16 KB (chunk-swizzled)
  __shared__ __align__(16) unsigned short Vs[128 * 64];       // 16 KB (chunk-swizzled)
  __shared__ __align__(16) unsigned short P_lds[8][16 * 72];  // 18 KB (pad 72: 2-way writes, free)
  unsigned short* Pw = &P_lds[w][0];

  s16x8 qf[4];
#pragma unroll
  for (int c = 0; c < 4; ++c)
    qf[c] = *(const s16x8*)(Qb + lo * HD_ + c * 32 + hi * 8);

  // per-thread staging geometry (loop-invariant)
  int kl4[2], kchg[2], vl4[2], vchg[2], kr[2], vd[2];
#pragma unroll
  for (int c = 0; c < 2; ++c) {
    int l4 = tid + c * 512;
    kl4[c] = l4; kr[c] = l4 >> 4;
    int ch = l4 & 15;
    kchg[c] = (ch & 8) | ((ch ^ kr[c]) & 7);
    vl4[c] = l4; vd[c] = l4 >> 3;
    vchg[c] = ((l4 & 7) ^ vd[c]) & 7;
  }

  f32x4 o[8] = {};
  float mrow[4], lrow[4];
#pragma unroll
  for (int r = 0; r < 4; ++r) { mrow[r] = -1e30f; lrow[r] = 0.f; }

  for (int t0 = 0; t0 < cnt; t0 += 64) {
    __syncthreads();  // all waves finished reading previous tile
    // stage K/V tile (pad rows beyond cnt read tiny-finite poison; bias kills them)
#pragma unroll
    for (int c = 0; c < 2; ++c) {
      __builtin_amdgcn_global_load_lds(
          (__attribute__((address_space(1))) void*)(Kb + (size_t)(t0 + kr[c]) * HD_ + kchg[c] * 8),
          (__attribute__((address_space(3))) void*)(Ks + kl4[c] * 8), 16, 0, 0);
      __builtin_amdgcn_global_load_lds(
          (__attribute__((address_space(1))) void*)(Vb + (size_t)vd[c] * S_ + t0 + vchg[c] * 8),
          (__attribute__((address_space(3))) void*)(Vs + vl4[c] * 8), 16, 0, 0);
    }
    asm volatile("s_waitcnt vmcnt(0)" ::: "memory");
    __syncthreads();

    // QK^T from LDS (exp2 domain; Q pre-scaled by log2e/sqrt(d))
    f32x4 s[4];
#pragma unroll
    for (int sf = 0; sf < 4; ++sf) {
      f32x4 sv = {};
      int row = sf * 16 + lo;
#pragma unroll
      for (int c = 0; c < 4; ++c) {
        int ch = c * 4 + hi;
        int chs = (ch & 8) | ((ch ^ lo) & 7);
        s16x8 kf = *(const s16x8*)(Ks + row * 128 + chs * 8);
        sv = __builtin_amdgcn_mfma_f32_16x16x32_bf16(qf[c], kf, sv, 0, 0, 0);
      }
      float bv = (t0 + row < cnt) ? 0.0f : -1e30f;  // pad columns only (last tile)
#pragma unroll
      for (int r = 0; r < 4; ++r) sv[r] += bv;
      s[sf] = sv;
    }
    // online softmax (rows = q hi*4+r, cols = k sf*16+lo)
    float tm[4];
#pragma unroll
    for (int r = 0; r < 4; ++r)
      tm[r] = fmaxf(fmaxf(s[0][r], s[1][r]), fmaxf(s[2][r], s[3][r]));
#pragma unroll
    for (int d = 1; d < 16; d <<= 1)
#pragma unroll
      for (int r = 0; r < 4; ++r) tm[r] = fmaxf(tm[r], __shfl_xor(tm[r], d));
    float dm = tm[0] - mrow[0];
#pragma unroll
    for (int r = 1; r < 4; ++r) dm = fmaxf(dm, tm[r] - mrow[r]);
    if (!__all(dm <= 8.0f)) {  // T13 defer-max
      float sc_[4];
#pragma unroll
      for (int r = 0; r < 4; ++r) {
        float mnew = fmaxf(mrow[r], tm[r]);
        sc_[r] = fexp2(mrow[r] - mnew);
        mrow[r] = mnew;
        lrow[r] *= sc_[r];
      }
#pragma unroll
      for (int df = 0; df < 8; ++df)
#pragma unroll
        for (int r = 0; r < 4; ++r) o[df][r] *= sc_[r];
    }
    float ts[4] = {0.f, 0.f, 0.f, 0.f};
#pragma unroll
    for (int sf = 0; sf < 4; ++sf)
#pragma unroll
      for (int r = 0; r < 4; ++r) {
        float p = fexp2(s[sf][r] - mrow[r]);
        ts[r] += p;
        Pw[(hi * 4 + r) * 72 + sf * 16 + lo] = f2bf(p);
      }
#pragma unroll
    for (int d = 1; d < 16; d <<= 1)
#pragma unroll
      for (int r = 0; r < 4; ++r) ts[r] += __shfl_xor(ts[r], d);
#pragma unroll
    for (int r = 0; r < 4; ++r) lrow[r] += ts[r];
    // P: C-layout -> A-layout via per-wave LDS
    s16x8 pa[2];
#pragma unroll
    for (int kk = 0; kk < 2; ++kk)
      pa[kk] = *(const s16x8*)(Pw + lo * 72 + kk * 32 + hi * 8);
    // PV from LDS
#pragma unroll
    for (int df = 0; df < 8; ++df) {
      int d = df * 16 + lo;
#pragma unroll
      for (int kk = 0; kk < 2; ++kk) {
        int ch = kk * 4 + hi;
        int chs = (ch ^ lo) & 7;
        s16x8 vf = *(const s16x8*)(Vs + d * 64 + chs * 8);
        o[df] = __builtin_amdgcn_mfma_f32_16x16x32_bf16(pa[kk], vf, o[df], 0, 0, 0);
      }
    }
  }
  float inv[4];
#pragma unroll
  for (int r = 0; r < 4; ++r) inv[r] = 1.0f / lrow[r];
#pragma unroll
  for (int df = 0; df < 8; ++df)
#pragma unroll
    for (int r = 0; r < 4; ++r)
      Out[(size_t)(b * S_ + q0 + hi * 4 + r) * DIM_ + h * HD_ + df * 16 + lo] =
          f2bf(o[df][r] * inv[r]);
}

extern "C" void kernel_launch(void* const* d_in, const int* in_sizes, int n_in,
                              void* d_out, int out_size, void* d_ws, size_t ws_size,
                              hipStream_t stream) {
  (void)in_sizes; (void)n_in; (void)out_size; (void)ws_size;
  const float* x    = (const float*)d_in[0];
  const float* ctab = (const float*)d_in[1];
  const float* stab = (const float*)d_in[2];
  const int*   mask = (const int*)d_in[3];
  const float* Wq   = (const float*)d_in[4];
  const float* Wk   = (const float*)d_in[5];
  const float* Wv   = (const float*)d_in[6];
  const float* Wo   = (const float*)d_in[7];

  unsigned short* x_bf = (unsigned short*)d_ws;        // 8388608 elems (reused as attn_out)
  unsigned short* Wqkv = x_bf + 8388608;               // 6291456
  unsigned short* Wob  = Wqkv + 6291456;               // 4194304
  unsigned short* QKV  = Wob + 4194304;                // 12582912
  unsigned short* Qt   = QKV + 12582912;               // 8388608
  unsigned short* Kt   = Qt + 8388608;                 // 2097152 (compacted K)
  unsigned short* Vt   = Kt + 2097152;                 // 2097152 (compacted V^T)

  // posmap/cnts live in d_out: dead until the final GEMM writes it (after attn reads cnts)
  int* posmap = (int*)d_out;                            // B_*S_ ints = 16 KB
  int* cnts   = posmap + B_ * S_;                       // B_ ints

  cast_all<<<9216, 256, 0, stream>>>(x, Wq, Wk, Wv, Wo, x_bf, Wqkv, Wob);
  scan_mask<<<B_, 256, 0, stream>>>(mask, posmap, cnts);

  gemm_bt<true><<<dim3(24, 32), 256, 0, stream>>>(x_bf, Wqkv, QKV, NQKV, DIM_);

  // Q pre-scale includes log2(e) for exp2-domain softmax
  rope_q<<<16384, 256, 0, stream>>>(QKV, ctab, stab, Qt,
                                    0.08838834764831845f * 1.4426950408889634f);
  rope_k<<<4096, 256, 0, stream>>>(QKV, ctab, stab, posmap, Kt);
  vtrans_kernel<<<dim3(32, 2, 8), 256, 0, stream>>>(QKV, posmap, Vt);

  attn_kernel<<<dim3(16, 16, 2), 512, 0, stream>>>(Qt, Kt, Vt, cnts, x_bf);

  gemm_bt<false><<<dim3(16, 32), 256, 0, stream>>>(x_bf, Wob, d_out, DIM_, DIM_);
}